// Round 1
// baseline (126.077 us; speedup 1.0000x reference)
//
#include <hip/hip_runtime.h>

#define BB 4
#define LL 512
#define KK 512
#define GT 512
#define GC 256
#define DD 64

// ---------------------------------------------------------------------------
// Kernel A: q_red[b,l,d] = sum_m x_query[b,l,m,d]   (x_query: [B,L,Gt,D])
// One block per (b,l). 256 threads: tid&15 -> float4 lane over D=64,
// tid>>4 -> m-group (16 groups). Fully coalesced float4 loads.
// ---------------------------------------------------------------------------
__global__ __launch_bounds__(256) void reduce_q(const float* __restrict__ xq,
                                                float* __restrict__ qred) {
    const int bl = blockIdx.x;           // 0..B*L-1
    const int tid = threadIdx.x;
    const int d4 = tid & 15;
    const int mg = tid >> 4;
    const float4* base = (const float4*)(xq + (size_t)bl * GT * DD);
    float4 acc = {0.f, 0.f, 0.f, 0.f};
    #pragma unroll 4
    for (int m = mg; m < GT; m += 16) {
        float4 v = base[m * 16 + d4];
        acc.x += v.x; acc.y += v.y; acc.z += v.z; acc.w += v.w;
    }
    __shared__ float s[16][64];
    s[mg][d4 * 4 + 0] = acc.x;
    s[mg][d4 * 4 + 1] = acc.y;
    s[mg][d4 * 4 + 2] = acc.z;
    s[mg][d4 * 4 + 3] = acc.w;
    __syncthreads();
    if (tid < 64) {
        float sum = 0.f;
        #pragma unroll
        for (int i = 0; i < 16; ++i) sum += s[i][tid];
        qred[(size_t)bl * DD + tid] = sum;
    }
}

// ---------------------------------------------------------------------------
// Kernel B: k_red[b,k,d] = sum_p context_key[b,k,p,d]   ([B,K,Gc,D])
// ---------------------------------------------------------------------------
__global__ __launch_bounds__(256) void reduce_k(const float* __restrict__ ck,
                                                float* __restrict__ kred) {
    const int bk = blockIdx.x;           // 0..B*K-1
    const int tid = threadIdx.x;
    const int d4 = tid & 15;
    const int pg = tid >> 4;
    const float4* base = (const float4*)(ck + (size_t)bk * GC * DD);
    float4 acc = {0.f, 0.f, 0.f, 0.f};
    #pragma unroll 4
    for (int p = pg; p < GC; p += 16) {
        float4 v = base[p * 16 + d4];
        acc.x += v.x; acc.y += v.y; acc.z += v.z; acc.w += v.w;
    }
    __shared__ float s[16][64];
    s[pg][d4 * 4 + 0] = acc.x;
    s[pg][d4 * 4 + 1] = acc.y;
    s[pg][d4 * 4 + 2] = acc.z;
    s[pg][d4 * 4 + 3] = acc.w;
    __syncthreads();
    if (tid < 64) {
        float sum = 0.f;
        #pragma unroll
        for (int i = 0; i < 16; ++i) sum += s[i][tid];
        kred[(size_t)bk * DD + tid] = sum;
    }
}

// ---------------------------------------------------------------------------
// Kernel C: per (b,l) row — scores (k<=l), softmax, weights x context_value,
// residual add, LayerNorm. 256 threads/block.
// ---------------------------------------------------------------------------
__global__ __launch_bounds__(256) void attn_fused(
    const float* __restrict__ x, const float* __restrict__ qred,
    const float* __restrict__ kred, const float* __restrict__ cv,
    const float* __restrict__ gamma, const float* __restrict__ beta,
    float* __restrict__ out) {
    const int bl = blockIdx.x;           // 0..B*L-1
    const int b = bl / LL;
    const int l = bl % LL;
    const int tid = threadIdx.x;

    __shared__ float q[DD];
    __shared__ float w[KK];
    __shared__ float redm[4], reds[4], red1[4], red2[4];

    if (tid < DD) q[tid] = qred[(size_t)bl * DD + tid];
    __syncthreads();

    // ---- scores: thread handles k = tid and k = tid+256 ----
    const float* krb = kred + (size_t)b * KK * DD;
    float sc[2];
    #pragma unroll
    for (int i = 0; i < 2; ++i) {
        const int k = tid + i * 256;
        float s = -1e30f;
        if (k <= l) {
            const float4* kr4 = (const float4*)(krb + (size_t)k * DD);
            float acc = 0.f;
            #pragma unroll
            for (int d = 0; d < 16; ++d) {
                float4 v = kr4[d];
                const float4* q4 = (const float4*)q;
                float4 qv = q4[d];
                acc += v.x * qv.x + v.y * qv.y + v.z * qv.z + v.w * qv.w;
            }
            s = acc;
        }
        sc[i] = s;
    }

    // ---- softmax over k<=l (masked entries underflow to exactly 0) ----
    float m = fmaxf(sc[0], sc[1]);
    #pragma unroll
    for (int off = 1; off < 64; off <<= 1) m = fmaxf(m, __shfl_xor(m, off));
    if ((tid & 63) == 0) redm[tid >> 6] = m;
    __syncthreads();
    m = fmaxf(fmaxf(redm[0], redm[1]), fmaxf(redm[2], redm[3]));

    const float e0 = expf(sc[0] - m);
    const float e1 = expf(sc[1] - m);
    float ssum = e0 + e1;
    #pragma unroll
    for (int off = 1; off < 64; off <<= 1) ssum += __shfl_xor(ssum, off);
    if ((tid & 63) == 0) reds[tid >> 6] = ssum;
    __syncthreads();
    ssum = reds[0] + reds[1] + reds[2] + reds[3];
    const float inv = 1.f / ssum;
    w[tid]       = e0 * inv;
    w[tid + 256] = e1 * inv;
    __syncthreads();

    // ---- attn_out row: acc[g] = sum_k w[k]*cv[b,k,g]; skip exact zeros ----
    const int nk = l + 1;
    const float2* cvb = (const float2*)(cv + (size_t)b * KK * GT);
    float2 acc = {0.f, 0.f};
    for (int k = 0; k < nk; ++k) {
        const float wk = w[k];            // LDS broadcast: uniform across block
        if (wk != 0.0f) {                 // uniform branch; skipping 0*v is exact
            float2 v = cvb[(size_t)k * (GT / 2) + tid];
            acc.x += wk * v.x;
            acc.y += wk * v.y;
        }
    }

    // ---- residual + LayerNorm over Gt=512 (2 elems per thread) ----
    const float2* x2 = (const float2*)(x + (size_t)bl * GT);
    const float2 xv = x2[tid];
    float2 y = {xv.x + acc.x, xv.y + acc.y};

    float s1 = y.x + y.y;
    float s2 = y.x * y.x + y.y * y.y;
    #pragma unroll
    for (int off = 1; off < 64; off <<= 1) {
        s1 += __shfl_xor(s1, off);
        s2 += __shfl_xor(s2, off);
    }
    if ((tid & 63) == 0) { red1[tid >> 6] = s1; red2[tid >> 6] = s2; }
    __syncthreads();
    s1 = red1[0] + red1[1] + red1[2] + red1[3];
    s2 = red2[0] + red2[1] + red2[2] + red2[3];

    const float mean = s1 * (1.f / GT);
    const float var = s2 * (1.f / GT) - mean * mean;
    const float rstd = rsqrtf(var + 1e-3f);

    const float2 ga = ((const float2*)gamma)[tid];
    const float2 be = ((const float2*)beta)[tid];
    float2 o;
    o.x = (y.x - mean) * rstd * ga.x + be.x;
    o.y = (y.y - mean) * rstd * ga.y + be.y;
    ((float2*)out)[(size_t)bl * (GT / 2) + tid] = o;
}

extern "C" void kernel_launch(void* const* d_in, const int* in_sizes, int n_in,
                              void* d_out, int out_size, void* d_ws, size_t ws_size,
                              hipStream_t stream) {
    const float* x     = (const float*)d_in[0];
    const float* xq    = (const float*)d_in[1];
    const float* ck    = (const float*)d_in[2];
    const float* cv    = (const float*)d_in[3];
    const float* gamma = (const float*)d_in[4];
    const float* beta  = (const float*)d_in[5];
    float* out = (float*)d_out;

    float* qred = (float*)d_ws;                 // B*L*D floats = 512 KB
    float* kred = qred + (size_t)BB * LL * DD;  // B*K*D floats = 512 KB

    reduce_q<<<BB * LL, 256, 0, stream>>>(xq, qred);
    reduce_k<<<BB * KK, 256, 0, stream>>>(ck, kred);
    attn_fused<<<BB * LL, 256, 0, stream>>>(x, qred, kred, cv, gamma, beta, out);
}

// Round 3
// 91.493 us; speedup vs baseline: 1.3780x; 1.3780x over previous
//
#include <hip/hip_runtime.h>

#define BB 4
#define LL 512
#define KK 512
#define GT 512
#define GC 256
#define DD 64

typedef float vf4 __attribute__((ext_vector_type(4)));

// ---------------------------------------------------------------------------
// Merged reduction kernel.
// Blocks [0, B*L)        : q_red[b,l,d] = sum_m x_query[b,l,m,d]
// Blocks [B*L, B*L+B*K)  : k_red[b,k,d] = sum_p context_key[b,k,p,d]
// 256 threads: tid&15 -> float4 lane over D=64, tid>>4 -> row-group of 16.
// A wave reads 1 KB contiguous per iteration (fully coalesced).
// ---------------------------------------------------------------------------
__global__ __launch_bounds__(256) void reduce_qk(const float* __restrict__ xq,
                                                 const float* __restrict__ ck,
                                                 float* __restrict__ qred,
                                                 float* __restrict__ kred) {
    const int bid = blockIdx.x;
    const int tid = threadIdx.x;
    const int d4 = tid & 15;
    const int g = tid >> 4;

    const vf4* p;
    int iters;
    float* dst;
    if (bid < BB * LL) {
        p = (const vf4*)(xq + (size_t)bid * GT * DD);
        iters = GT / 16;                 // 32
        dst = qred + (size_t)bid * DD;
    } else {
        const int bk = bid - BB * LL;
        p = (const vf4*)(ck + (size_t)bk * GC * DD);
        iters = GC / 16;                 // 16
        dst = kred + (size_t)bk * DD;
    }
    p += g * 16 + d4;

    vf4 acc = {0.f, 0.f, 0.f, 0.f};
    #pragma unroll 8
    for (int it = 0; it < iters; ++it) {
        vf4 v = __builtin_nontemporal_load(p);
        p += 256;                        // 16 rows * 16 float4
        acc += v;
    }

    __shared__ float s[16][64];
    s[g][d4 * 4 + 0] = acc.x;
    s[g][d4 * 4 + 1] = acc.y;
    s[g][d4 * 4 + 2] = acc.z;
    s[g][d4 * 4 + 3] = acc.w;
    __syncthreads();
    if (tid < 64) {
        float sum = 0.f;
        #pragma unroll
        for (int i = 0; i < 16; ++i) sum += s[i][tid];
        dst[tid] = sum;
    }
}

// ---------------------------------------------------------------------------
// Fused attention tail: scores (k<=l), softmax, sparse weights x value,
// residual add, LayerNorm. One block per (b,l), 256 threads.
// Softmax is near-one-hot (score sigma ~2900): masked/low scores underflow
// expf to exactly 0.0f, identical to the reference path. We build a bitmask
// of nonzero weights and iterate only set bits (deterministic ascending k).
// ---------------------------------------------------------------------------
__global__ __launch_bounds__(256) void attn_fused(
    const float* __restrict__ x, const float* __restrict__ qred,
    const float* __restrict__ kred, const float* __restrict__ cv,
    const float* __restrict__ gamma, const float* __restrict__ beta,
    float* __restrict__ out) {
    const int bl = blockIdx.x;           // 0..B*L-1
    const int b = bl / LL;
    const int l = bl % LL;
    const int tid = threadIdx.x;
    const int wv = tid >> 6;             // wave id 0..3

    __shared__ float q[DD];
    __shared__ float w[KK];
    __shared__ unsigned long long smask[8];
    __shared__ float redm[4], reds[4], red1[4], red2[4];

    if (tid < DD) q[tid] = qred[(size_t)bl * DD + tid];
    __syncthreads();

    // ---- scores: thread handles k = tid and k = tid+256 ----
    const float* krb = kred + (size_t)b * KK * DD;
    float sc[2];
    #pragma unroll
    for (int i = 0; i < 2; ++i) {
        const int k = tid + i * 256;
        float s = -1e30f;
        if (k <= l) {
            const float4* kr4 = (const float4*)(krb + (size_t)k * DD);
            const float4* q4 = (const float4*)q;
            float acc = 0.f;
            #pragma unroll
            for (int d = 0; d < 16; ++d) {
                float4 v = kr4[d];
                float4 qv = q4[d];
                acc += v.x * qv.x + v.y * qv.y + v.z * qv.z + v.w * qv.w;
            }
            s = acc;
        }
        sc[i] = s;
    }

    // ---- softmax max ----
    float m = fmaxf(sc[0], sc[1]);
    #pragma unroll
    for (int off = 1; off < 64; off <<= 1) m = fmaxf(m, __shfl_xor(m, off));
    if ((tid & 63) == 0) redm[wv] = m;
    __syncthreads();
    m = fmaxf(fmaxf(redm[0], redm[1]), fmaxf(redm[2], redm[3]));

    // ---- exp + sum ----
    const float e0 = expf(sc[0] - m);
    const float e1 = expf(sc[1] - m);
    float ssum = e0 + e1;
    #pragma unroll
    for (int off = 1; off < 64; off <<= 1) ssum += __shfl_xor(ssum, off);
    if ((tid & 63) == 0) reds[wv] = ssum;

    // ---- nonzero-weight bitmask (wave wv covers k=wv*64+lane and +256) ----
    const unsigned long long b0 = __ballot(e0 > 0.f);
    const unsigned long long b1 = __ballot(e1 > 0.f);
    if ((tid & 63) == 0) { smask[wv] = b0; smask[wv + 4] = b1; }
    __syncthreads();
    ssum = reds[0] + reds[1] + reds[2] + reds[3];
    const float inv = 1.f / ssum;
    w[tid]       = e0 * inv;
    w[tid + 256] = e1 * inv;
    __syncthreads();

    // ---- attn_out row: only nonzero weights (typically 1-3 of 512) ----
    const float2* cvb = (const float2*)(cv + (size_t)b * KK * GT);
    float2 acc = {0.f, 0.f};
    const int nwords = (l >> 6) + 1;
    for (int wd = 0; wd < nwords; ++wd) {
        unsigned long long msk = smask[wd];
        while (msk) {
            const int k = (wd << 6) + __builtin_ctzll(msk);
            msk &= msk - 1;
            const float wk = w[k];
            const float2 v = cvb[(size_t)k * (GT / 2) + tid];
            acc.x += wk * v.x;
            acc.y += wk * v.y;
        }
    }

    // ---- residual + LayerNorm over Gt=512 (2 elems per thread) ----
    const float2 xv = ((const float2*)(x + (size_t)bl * GT))[tid];
    float2 y = {xv.x + acc.x, xv.y + acc.y};

    float s1 = y.x + y.y;
    float s2 = y.x * y.x + y.y * y.y;
    #pragma unroll
    for (int off = 1; off < 64; off <<= 1) {
        s1 += __shfl_xor(s1, off);
        s2 += __shfl_xor(s2, off);
    }
    if ((tid & 63) == 0) { red1[wv] = s1; red2[wv] = s2; }
    __syncthreads();
    s1 = red1[0] + red1[1] + red1[2] + red1[3];
    s2 = red2[0] + red2[1] + red2[2] + red2[3];

    const float mean = s1 * (1.f / GT);
    const float var = s2 * (1.f / GT) - mean * mean;
    const float rstd = rsqrtf(var + 1e-3f);

    const float2 ga = ((const float2*)gamma)[tid];
    const float2 be = ((const float2*)beta)[tid];
    float2 o;
    o.x = (y.x - mean) * rstd * ga.x + be.x;
    o.y = (y.y - mean) * rstd * ga.y + be.y;
    ((float2*)out)[(size_t)bl * (GT / 2) + tid] = o;
}

extern "C" void kernel_launch(void* const* d_in, const int* in_sizes, int n_in,
                              void* d_out, int out_size, void* d_ws, size_t ws_size,
                              hipStream_t stream) {
    const float* x     = (const float*)d_in[0];
    const float* xq    = (const float*)d_in[1];
    const float* ck    = (const float*)d_in[2];
    const float* cv    = (const float*)d_in[3];
    const float* gamma = (const float*)d_in[4];
    const float* beta  = (const float*)d_in[5];
    float* out = (float*)d_out;

    float* qred = (float*)d_ws;                 // B*L*D floats = 512 KB
    float* kred = qred + (size_t)BB * LL * DD;  // B*K*D floats = 512 KB

    reduce_qk<<<BB * LL + BB * KK, 256, 0, stream>>>(xq, ck, qred, kred);
    attn_fused<<<BB * LL, 256, 0, stream>>>(x, qred, kred, cv, gamma, beta, out);
}

// Round 4
// 89.575 us; speedup vs baseline: 1.4075x; 1.0214x over previous
//
#include <hip/hip_runtime.h>

#define BB 4
#define LL 512
#define KK 512
#define GT 512
#define GC 256
#define DD 64

typedef float vf4 __attribute__((ext_vector_type(4)));

// ---------------------------------------------------------------------------
// Merged reduction kernel.
// Blocks [0, B*L)        : q_red[b,l,d] = sum_m x_query[b,l,m,d]
// Blocks [B*L, B*L+B*K)  : k_red[b,k,d] = sum_p context_key[b,k,p,d]
// 256 threads: tid&15 -> float4 lane over D=64, tid>>4 -> row-group of 16.
// A wave reads 1 KB contiguous per iteration (fully coalesced, nontemporal).
// ---------------------------------------------------------------------------
__global__ __launch_bounds__(256) void reduce_qk(const float* __restrict__ xq,
                                                 const float* __restrict__ ck,
                                                 float* __restrict__ qred,
                                                 float* __restrict__ kred) {
    const int bid = blockIdx.x;
    const int tid = threadIdx.x;
    const int d4 = tid & 15;
    const int g = tid >> 4;

    const vf4* p;
    int iters;
    float* dst;
    if (bid < BB * LL) {
        p = (const vf4*)(xq + (size_t)bid * GT * DD);
        iters = GT / 16;                 // 32
        dst = qred + (size_t)bid * DD;
    } else {
        const int bk = bid - BB * LL;
        p = (const vf4*)(ck + (size_t)bk * GC * DD);
        iters = GC / 16;                 // 16
        dst = kred + (size_t)bk * DD;
    }
    p += g * 16 + d4;

    vf4 acc = {0.f, 0.f, 0.f, 0.f};
    #pragma unroll 16
    for (int it = 0; it < iters; ++it) {
        vf4 v = __builtin_nontemporal_load(p);
        p += 256;                        // 16 rows * 16 float4
        acc += v;
    }

    __shared__ float s[16][64];
    s[g][d4 * 4 + 0] = acc.x;
    s[g][d4 * 4 + 1] = acc.y;
    s[g][d4 * 4 + 2] = acc.z;
    s[g][d4 * 4 + 3] = acc.w;
    __syncthreads();
    if (tid < 64) {
        float sum = 0.f;
        #pragma unroll
        for (int i = 0; i < 16; ++i) sum += s[i][tid];
        dst[tid] = sum;
    }
}

// ---------------------------------------------------------------------------
// Fused attention tail: scores (k<=l), softmax, sparse weights x value,
// residual add, LayerNorm. One block per (b,l), 256 threads.
// q is held in REGISTERS (uniform across threads -> L1 broadcast), not LDS:
// the score phase has zero LDS traffic.
// Softmax is near-one-hot (score sigma ~2900): masked/low scores underflow
// expf to exactly 0.0f, identical to the reference path. We build a bitmask
// of nonzero weights and iterate only set bits (deterministic ascending k).
// ---------------------------------------------------------------------------
__global__ __launch_bounds__(256) void attn_fused(
    const float* __restrict__ x, const float* __restrict__ qred,
    const float* __restrict__ kred, const float* __restrict__ cv,
    const float* __restrict__ gamma, const float* __restrict__ beta,
    float* __restrict__ out) {
    const int bl = blockIdx.x;           // 0..B*L-1
    const int b = bl >> 9;
    const int l = bl & (LL - 1);
    const int tid = threadIdx.x;
    const int wv = tid >> 6;             // wave id 0..3

    __shared__ float w[KK];
    __shared__ unsigned long long smask[8];
    __shared__ float redm[4], reds[4], red1[4], red2[4];

    // ---- q into registers (same addresses across all threads) ----
    const vf4* q4 = (const vf4*)(qred + (size_t)bl * DD);
    vf4 q[16];
    #pragma unroll
    for (int d = 0; d < 16; ++d) q[d] = q4[d];

    // ---- scores: thread handles k = tid and k = tid+256 ----
    const float* krb = kred + (size_t)b * KK * DD;
    float sc[2];
    #pragma unroll
    for (int i = 0; i < 2; ++i) {
        const int k = tid + i * 256;
        float s = -1e30f;
        if (k <= l) {
            const vf4* kr4 = (const vf4*)(krb + (size_t)k * DD);
            float acc = 0.f;
            #pragma unroll
            for (int d = 0; d < 16; ++d) {
                vf4 kv = kr4[d];
                acc += kv.x * q[d].x + kv.y * q[d].y + kv.z * q[d].z + kv.w * q[d].w;
            }
            s = acc;
        }
        sc[i] = s;
    }

    // ---- softmax max ----
    float m = fmaxf(sc[0], sc[1]);
    #pragma unroll
    for (int off = 1; off < 64; off <<= 1) m = fmaxf(m, __shfl_xor(m, off));
    if ((tid & 63) == 0) redm[wv] = m;
    __syncthreads();
    m = fmaxf(fmaxf(redm[0], redm[1]), fmaxf(redm[2], redm[3]));

    // ---- exp + sum ----
    const float e0 = expf(sc[0] - m);
    const float e1 = expf(sc[1] - m);
    float ssum = e0 + e1;
    #pragma unroll
    for (int off = 1; off < 64; off <<= 1) ssum += __shfl_xor(ssum, off);
    if ((tid & 63) == 0) reds[wv] = ssum;

    // ---- nonzero-weight bitmask (wave wv covers k=wv*64+lane and +256) ----
    const unsigned long long b0 = __ballot(e0 > 0.f);
    const unsigned long long b1 = __ballot(e1 > 0.f);
    if ((tid & 63) == 0) { smask[wv] = b0; smask[wv + 4] = b1; }
    __syncthreads();
    ssum = reds[0] + reds[1] + reds[2] + reds[3];
    const float inv = 1.f / ssum;
    w[tid]       = e0 * inv;
    w[tid + 256] = e1 * inv;
    __syncthreads();

    // ---- attn_out row: only nonzero weights (typically 1-3 of 512) ----
    const float2* cvb = (const float2*)(cv + (size_t)b * KK * GT);
    float2 acc = {0.f, 0.f};
    const int nwords = (l >> 6) + 1;
    for (int wd = 0; wd < nwords; ++wd) {
        unsigned long long msk = smask[wd];
        while (msk) {
            const int k = (wd << 6) + __builtin_ctzll(msk);
            msk &= msk - 1;
            const float wk = w[k];
            const float2 v = cvb[(size_t)k * (GT / 2) + tid];
            acc.x += wk * v.x;
            acc.y += wk * v.y;
        }
    }

    // ---- residual + LayerNorm over Gt=512 (2 elems per thread) ----
    const float2 xv = ((const float2*)(x + (size_t)bl * GT))[tid];
    float2 y = {xv.x + acc.x, xv.y + acc.y};

    float s1 = y.x + y.y;
    float s2 = y.x * y.x + y.y * y.y;
    #pragma unroll
    for (int off = 1; off < 64; off <<= 1) {
        s1 += __shfl_xor(s1, off);
        s2 += __shfl_xor(s2, off);
    }
    if ((tid & 63) == 0) { red1[wv] = s1; red2[wv] = s2; }
    __syncthreads();
    s1 = red1[0] + red1[1] + red1[2] + red1[3];
    s2 = red2[0] + red2[1] + red2[2] + red2[3];

    const float mean = s1 * (1.f / GT);
    const float var = s2 * (1.f / GT) - mean * mean;
    const float rstd = rsqrtf(var + 1e-3f);

    const float2 ga = ((const float2*)gamma)[tid];
    const float2 be = ((const float2*)beta)[tid];
    float2 o;
    o.x = (y.x - mean) * rstd * ga.x + be.x;
    o.y = (y.y - mean) * rstd * ga.y + be.y;
    ((float2*)out)[(size_t)bl * (GT / 2) + tid] = o;
}

extern "C" void kernel_launch(void* const* d_in, const int* in_sizes, int n_in,
                              void* d_out, int out_size, void* d_ws, size_t ws_size,
                              hipStream_t stream) {
    const float* x     = (const float*)d_in[0];
    const float* xq    = (const float*)d_in[1];
    const float* ck    = (const float*)d_in[2];
    const float* cv    = (const float*)d_in[3];
    const float* gamma = (const float*)d_in[4];
    const float* beta  = (const float*)d_in[5];
    float* out = (float*)d_out;

    float* qred = (float*)d_ws;                 // B*L*D floats = 512 KB
    float* kred = qred + (size_t)BB * LL * DD;  // B*K*D floats = 512 KB

    reduce_qk<<<BB * LL + BB * KK, 256, 0, stream>>>(xq, ck, qred, kred);
    attn_fused<<<BB * LL, 256, 0, stream>>>(x, qred, kred, cv, gamma, beta, out);
}

// Round 5
// 77.687 us; speedup vs baseline: 1.6229x; 1.1530x over previous
//
#include <hip/hip_runtime.h>

#define BB 4
#define LL 512
#define KK 512
#define GT 512
#define GC 256
#define DD 64

typedef float vf4 __attribute__((ext_vector_type(4)));

// ---------------------------------------------------------------------------
// Merged reduction kernel.
// Blocks [0, B*L)        : q_red[b,l,d] = sum_m x_query[b,l,m,d]  -> linear
// Blocks [B*L, B*L+B*K)  : k_red[b,k,d] = sum_p context_key[b,k,p,d]
//                          -> TRANSPOSED kredT[b][d>>2][k][d&3] so the score
//                             phase reads are lane-coalesced vf4s.
// 256 threads: tid&15 -> float4 lane over D=64, tid>>4 -> row-group of 16.
// A wave reads 1 KB contiguous per iteration (fully coalesced, nontemporal).
// ---------------------------------------------------------------------------
__global__ __launch_bounds__(256) void reduce_qk(const float* __restrict__ xq,
                                                 const float* __restrict__ ck,
                                                 float* __restrict__ qred,
                                                 float* __restrict__ kredT) {
    const int bid = blockIdx.x;
    const int tid = threadIdx.x;
    const int d4 = tid & 15;
    const int g = tid >> 4;

    const vf4* p;
    int iters;
    if (bid < BB * LL) {
        p = (const vf4*)(xq + (size_t)bid * GT * DD);
        iters = GT / 16;                 // 32
    } else {
        const int bk = bid - BB * LL;
        p = (const vf4*)(ck + (size_t)bk * GC * DD);
        iters = GC / 16;                 // 16
    }
    p += g * 16 + d4;

    vf4 acc = {0.f, 0.f, 0.f, 0.f};
    #pragma unroll 16
    for (int it = 0; it < iters; ++it) {
        vf4 v = __builtin_nontemporal_load(p);
        p += 256;                        // 16 rows * 16 float4
        acc += v;
    }

    __shared__ float s[16][64];
    s[g][d4 * 4 + 0] = acc.x;
    s[g][d4 * 4 + 1] = acc.y;
    s[g][d4 * 4 + 2] = acc.z;
    s[g][d4 * 4 + 3] = acc.w;
    __syncthreads();
    if (tid < 64) {
        float sum = 0.f;
        #pragma unroll
        for (int i = 0; i < 16; ++i) sum += s[i][tid];
        if (bid < BB * LL) {
            qred[(size_t)bid * DD + tid] = sum;
        } else {
            const int bk = bid - BB * LL;
            const int b = bk >> 9;
            const int k = bk & (KK - 1);
            // kredT element (b, k, d=tid): plane d>>2, slot k*4 + (d&3)
            kredT[(size_t)b * (16 * KK * 4) + (size_t)(tid >> 2) * (KK * 4)
                  + k * 4 + (tid & 3)] = sum;
        }
    }
}

// ---------------------------------------------------------------------------
// Fused attention tail: scores (k<=l), softmax, sparse weights x value,
// residual add, LayerNorm. One block per (b,l), 256 threads.
// q in registers (uniform address -> broadcast). kredT reads are coalesced:
// per d-chunk, lane k reads the vf4 at k*16B inside the chunk plane.
// Softmax is near-one-hot (score sigma ~2900): masked/low scores underflow
// expf to exactly 0.0f, identical to the reference path. We build a bitmask
// of nonzero weights and iterate only set bits (deterministic ascending k).
// ---------------------------------------------------------------------------
__global__ __launch_bounds__(256) void attn_fused(
    const float* __restrict__ x, const float* __restrict__ qred,
    const float* __restrict__ kredT, const float* __restrict__ cv,
    const float* __restrict__ gamma, const float* __restrict__ beta,
    float* __restrict__ out) {
    const int bl = blockIdx.x;           // 0..B*L-1
    const int b = bl >> 9;
    const int l = bl & (LL - 1);
    const int tid = threadIdx.x;
    const int wv = tid >> 6;             // wave id 0..3

    __shared__ float w[KK];
    __shared__ unsigned long long smask[8];
    __shared__ float redm[4], reds[4], red1[4], red2[4];

    // ---- q into registers (same addresses across all threads) ----
    const vf4* q4 = (const vf4*)(qred + (size_t)bl * DD);
    vf4 q[16];
    #pragma unroll
    for (int d = 0; d < 16; ++d) q[d] = q4[d];

    // ---- scores: thread handles k = tid and k = tid+256, coalesced kredT ----
    const float* ktb = kredT + (size_t)b * (16 * KK * 4);
    float sc[2];
    #pragma unroll
    for (int i = 0; i < 2; ++i) {
        const int k = tid + i * 256;
        float s = -1e30f;
        if (k <= l) {
            float acc = 0.f;
            #pragma unroll
            for (int dc = 0; dc < 16; ++dc) {
                vf4 kv = *(const vf4*)(ktb + (size_t)dc * (KK * 4) + k * 4);
                acc += kv.x * q[dc].x + kv.y * q[dc].y + kv.z * q[dc].z + kv.w * q[dc].w;
            }
            s = acc;
        }
        sc[i] = s;
    }

    // ---- softmax max ----
    float m = fmaxf(sc[0], sc[1]);
    #pragma unroll
    for (int off = 1; off < 64; off <<= 1) m = fmaxf(m, __shfl_xor(m, off));
    if ((tid & 63) == 0) redm[wv] = m;
    __syncthreads();
    m = fmaxf(fmaxf(redm[0], redm[1]), fmaxf(redm[2], redm[3]));

    // ---- exp + sum ----
    const float e0 = expf(sc[0] - m);
    const float e1 = expf(sc[1] - m);
    float ssum = e0 + e1;
    #pragma unroll
    for (int off = 1; off < 64; off <<= 1) ssum += __shfl_xor(ssum, off);
    if ((tid & 63) == 0) reds[wv] = ssum;

    // ---- nonzero-weight bitmask (wave wv covers k=wv*64+lane and +256) ----
    const unsigned long long b0 = __ballot(e0 > 0.f);
    const unsigned long long b1 = __ballot(e1 > 0.f);
    if ((tid & 63) == 0) { smask[wv] = b0; smask[wv + 4] = b1; }
    __syncthreads();
    ssum = reds[0] + reds[1] + reds[2] + reds[3];
    const float inv = 1.f / ssum;
    w[tid]       = e0 * inv;
    w[tid + 256] = e1 * inv;
    __syncthreads();

    // ---- attn_out row: only nonzero weights (typically 1-3 of 512) ----
    const float2* cvb = (const float2*)(cv + (size_t)b * KK * GT);
    float2 acc = {0.f, 0.f};
    const int nwords = (l >> 6) + 1;
    for (int wd = 0; wd < nwords; ++wd) {
        unsigned long long msk = smask[wd];
        while (msk) {
            const int k = (wd << 6) + __builtin_ctzll(msk);
            msk &= msk - 1;
            const float wk = w[k];
            const float2 v = cvb[(size_t)k * (GT / 2) + tid];
            acc.x += wk * v.x;
            acc.y += wk * v.y;
        }
    }

    // ---- residual + LayerNorm over Gt=512 (2 elems per thread) ----
    const float2 xv = ((const float2*)(x + (size_t)bl * GT))[tid];
    float2 y = {xv.x + acc.x, xv.y + acc.y};

    float s1 = y.x + y.y;
    float s2 = y.x * y.x + y.y * y.y;
    #pragma unroll
    for (int off = 1; off < 64; off <<= 1) {
        s1 += __shfl_xor(s1, off);
        s2 += __shfl_xor(s2, off);
    }
    if ((tid & 63) == 0) { red1[wv] = s1; red2[wv] = s2; }
    __syncthreads();
    s1 = red1[0] + red1[1] + red1[2] + red1[3];
    s2 = red2[0] + red2[1] + red2[2] + red2[3];

    const float mean = s1 * (1.f / GT);
    const float var = s2 * (1.f / GT) - mean * mean;
    const float rstd = rsqrtf(var + 1e-3f);

    const float2 ga = ((const float2*)gamma)[tid];
    const float2 be = ((const float2*)beta)[tid];
    float2 o;
    o.x = (y.x - mean) * rstd * ga.x + be.x;
    o.y = (y.y - mean) * rstd * ga.y + be.y;
    ((float2*)out)[(size_t)bl * (GT / 2) + tid] = o;
}

extern "C" void kernel_launch(void* const* d_in, const int* in_sizes, int n_in,
                              void* d_out, int out_size, void* d_ws, size_t ws_size,
                              hipStream_t stream) {
    const float* x     = (const float*)d_in[0];
    const float* xq    = (const float*)d_in[1];
    const float* ck    = (const float*)d_in[2];
    const float* cv    = (const float*)d_in[3];
    const float* gamma = (const float*)d_in[4];
    const float* beta  = (const float*)d_in[5];
    float* out = (float*)d_out;

    float* qred  = (float*)d_ws;                 // B*L*D floats = 512 KB
    float* kredT = qred + (size_t)BB * LL * DD;  // B*16*K*4 floats = 512 KB

    reduce_qk<<<BB * LL + BB * KK, 256, 0, stream>>>(xq, ck, qred, kredT);
    attn_fused<<<BB * LL, 256, 0, stream>>>(x, qred, kredT, cv, gamma, beta, out);
}